// Round 10
// baseline (851.920 us; speedup 1.0000x reference)
//
#include <hip/hip_runtime.h>
#include <math.h>

typedef unsigned short ushort_t;
typedef unsigned int uint_t;
typedef __bf16 bf16x4 __attribute__((ext_vector_type(4)));
typedef __bf16 bf16x8 __attribute__((ext_vector_type(8)));
typedef float f32x4 __attribute__((ext_vector_type(4)));

#define T_SEQ   1536
#define NB      2
#define MROWS   3072
#define DMODEL  512
#define NHEADS  8
#define DHEAD   64
#define DFF     2048
#define DMOTION 256
#define NLAYERS 6
#define PERIODN 15
#define CTXF    10
#define THRW    128
#define KIN     384           // 262 zero-padded to multiple of 128

__device__ __forceinline__ float bf2f(ushort_t u) { return __uint_as_float((uint_t)u << 16); }
__device__ __forceinline__ ushort_t f2bf(float f) {
    uint_t x = __float_as_uint(f);
    return (ushort_t)((x + 0x7fffu + ((x >> 16) & 1u)) >> 16);   // RNE
}

// Direct HBM->LDS async copy, 16 B per lane. LDS dest = wave-uniform base
// + lane*16 (HW); global src is per-lane -> swizzled layouts via source.
__device__ __forceinline__ void gl2lds(const ushort_t* g, ushort_t* l) {
    __builtin_amdgcn_global_load_lds((const __attribute__((address_space(1))) void*)g,
                                     (__attribute__((address_space(3))) void*)l, 16, 0, 0);
}

// ---------------------------------------------------------------------------
// PE table (15 distinct rows)
// ---------------------------------------------------------------------------
__global__ __launch_bounds__(256) void pe_k(float* __restrict__ pe) {
    int idx = blockIdx.x * 256 + threadIdx.x;
    if (idx >= PERIODN * DMODEL) return;
    int p = idx / DMODEL, c = idx % DMODEL;
    int j = (c < DMODEL / 2) ? c : (c - DMODEL / 2);
    float div = __expf(-logf(10000.0f) * (2.0f * (float)j) / (float)DMODEL);
    float ang = (float)p * div;
    pe[idx] = (c < DMODEL / 2) ? sinf(ang) : cosf(ang);
}

// ---------------------------------------------------------------------------
// Encoder input (bf16, K padded to 384) + mask output
// ---------------------------------------------------------------------------
__global__ __launch_bounds__(256) void build_k(const float* __restrict__ motion,
                                               const float* __restrict__ traj,
                                               ushort_t* __restrict__ hin,
                                               float* __restrict__ mask_out) {
    int idx = blockIdx.x * 256 + threadIdx.x;
    if (idx >= MROWS * KIN) return;
    int row = idx / KIN, c = idx % KIN;
    int t = row % T_SEQ;
    float mv = (t < CTXF || t == T_SEQ - 1) ? 1.0f : 0.0f;
    float val;
    if (c < DMOTION)            val = motion[(size_t)row * DMOTION + c] * mv;
    else if (c < DMOTION + 5)   val = traj[(size_t)row * 5 + (c - DMOTION)];
    else if (c == DMOTION + 5)  val = mv;
    else                        val = 0.0f;
    hin[idx] = f2bf(val);
    if (c == 0) mask_out[row] = mv;
}

// ---------------------------------------------------------------------------
// Transpose-convert: src f32 [K][N] -> dst bf16 [N][Kpad] (zero pad k>=K).
// ---------------------------------------------------------------------------
__global__ __launch_bounds__(256)
void tconv_k(const float* __restrict__ src, size_t sstride,
             ushort_t* __restrict__ dst, size_t dstride,
             int K, int N, int Kpad) {
    __shared__ float t[32][33];
    src += (size_t)blockIdx.z * sstride;
    dst += (size_t)blockIdx.z * dstride;
    const int kb = blockIdx.y * 32, nb = blockIdx.x * 32;
    const int tx = threadIdx.x & 31, ty = threadIdx.x >> 5;
#pragma unroll
    for (int i = 0; i < 4; ++i) {
        int k = kb + ty + i * 8, n = nb + tx;
        t[ty + i * 8][tx] = (k < K && n < N) ? src[(size_t)k * N + n] : 0.0f;
    }
    __syncthreads();
#pragma unroll
    for (int i = 0; i < 4; ++i) {
        int n = nb + ty + i * 8, kk = kb + tx;
        if (n < N && kk < Kpad) dst[(size_t)n * Kpad + kk] = f2bf(t[tx][ty + i * 8]);
    }
}

// QKV concat transpose: z = layer*3+seg; dst = qkvt[l][seg*512 + n][k]
__global__ __launch_bounds__(256)
void tconv_qkv_k(const float* __restrict__ wq, const float* __restrict__ wk,
                 const float* __restrict__ wv, ushort_t* __restrict__ qkvt) {
    __shared__ float t[32][33];
    const int z = blockIdx.z, s = z % 3, l = z / 3;
    const float* src = (s == 0 ? wq : s == 1 ? wk : wv) + (size_t)l * DMODEL * DMODEL;
    ushort_t* dst = qkvt + (size_t)z * DMODEL * DMODEL;
    const int kb = blockIdx.y * 32, nb = blockIdx.x * 32;
    const int tx = threadIdx.x & 31, ty = threadIdx.x >> 5;
#pragma unroll
    for (int i = 0; i < 4; ++i)
        t[ty + i * 8][tx] = src[(size_t)(kb + ty + i * 8) * DMODEL + nb + tx];
    __syncthreads();
#pragma unroll
    for (int i = 0; i < 4; ++i)
        dst[(size_t)(nb + ty + i * 8) * DMODEL + kb + tx] = f2bf(t[tx][ty + i * 8]);
}

__global__ __launch_bounds__(256)
void bcat_k(const float* __restrict__ bq, const float* __restrict__ bk,
            const float* __restrict__ bv, float* __restrict__ bqkv) {
    int idx = blockIdx.x * 256 + threadIdx.x;
    if (idx >= NLAYERS * 3 * DMODEL) return;
    int l = idx / (3 * DMODEL), n = idx % (3 * DMODEL);
    int s = n >> 9, c = n & 511;
    const float* b = (s == 0 ? bq : s == 1 ? bk : bv);
    bqkv[idx] = b[l * DMODEL + c];
}

// ---------------------------------------------------------------------------
// Pipelined split-K bf16 MFMA GEMM (round-9 proven): 32x64 tile, 4 waves
// each owning a 32-wide k-slice of BK=128. Double-buffered LINEAR LDS via
// global_load_lds (zero staging VGPRs); source-XOR swizzle for conflicts.
// ACT: 0 none, 1 leaky, 2 relu, 3 final-blend (v = res*mv + v*(1-mv)).
// ---------------------------------------------------------------------------
#define CL  68      // f32 reduce-buffer row stride
template <int ACT, bool RES, bool PE, bool OUTBF>
__global__ __launch_bounds__(256)
void qgemm_k(const ushort_t* __restrict__ A, int K,
             const ushort_t* __restrict__ Wt,
             const float* __restrict__ bias,
             const float* __restrict__ res,
             const float* __restrict__ pe15,
             void* __restrict__ Cout, int N) {
    __shared__ ushort_t smem[2][(32 + 64) * 128];   // 2 x 24 KB, A | B, linear
    const int tid = threadIdx.x;
    const int lane = tid & 63, wid = tid >> 6;
    const int m0 = blockIdx.y * 32, n0 = blockIdx.x * 64;
    const int l4 = lane >> 4, l15 = lane & 15;
    const int lrow = lane >> 4;          // row within a 4-row stage instruction
    const int lu   = lane & 15;          // swizzled 16B-unit index u'

    f32x4 acc[2][4];
#pragma unroll
    for (int m = 0; m < 2; ++m)
#pragma unroll
        for (int n = 0; n < 4; ++n) acc[m][n] = (f32x4){0.f, 0.f, 0.f, 0.f};

    const int niter = K >> 7;                       // K multiple of 128

    auto stage = [&](int buf, int k0) {
        ushort_t* dst = &smem[buf][0];
#pragma unroll
        for (int j = 0; j < 6; ++j) {
            const int inst = wid * 6 + j;
            if (inst < 8) {
                const int row = inst * 4 + lrow;            // A row 0..31
                const int u = lu ^ (row & 15);
                gl2lds(A + (size_t)(m0 + row) * K + k0 + u * 8, dst + inst * 512);
            } else {
                const int bi = inst - 8;
                const int row = bi * 4 + lrow;              // B row 0..63
                const int u = lu ^ (row & 15);
                gl2lds(Wt + (size_t)(n0 + row) * K + k0 + u * 8,
                       dst + 32 * 128 + bi * 512);
            }
        }
    };

    const int kbyte = wid * 64;                     // this wave's k-slice (bytes)
    auto rdfrag = [&](const ushort_t* t, int row) -> bf16x8 {
        const int off0 = kbyte + l4 * 8;
        const int off1 = kbyte + 32 + l4 * 8;
        const int a0 = row * 256 + (((off0 & ~15) ^ ((row & 15) << 4)) | (off0 & 15));
        const int a1 = row * 256 + (((off1 & ~15) ^ ((row & 15) << 4)) | (off1 & 15));
        bf16x4 lo = *(const bf16x4*)((const char*)t + a0);
        bf16x4 hi = *(const bf16x4*)((const char*)t + a1);
        return __builtin_shufflevector(lo, hi, 0, 1, 2, 3, 4, 5, 6, 7);
    };

    stage(0, 0);
    __syncthreads();
    int cur = 0;
    for (int t = 0; t < niter; ++t) {
        if (t + 1 < niter) stage(cur ^ 1, (t + 1) << 7);
        const ushort_t* As = &smem[cur][0];
        const ushort_t* Bs = &smem[cur][32 * 128];
        bf16x8 af[2], bf[4];
#pragma unroll
        for (int m = 0; m < 2; ++m) af[m] = rdfrag(As, m * 16 + l15);
#pragma unroll
        for (int n = 0; n < 4; ++n) bf[n] = rdfrag(Bs, n * 16 + l15);
#pragma unroll
        for (int m = 0; m < 2; ++m)
#pragma unroll
            for (int n = 0; n < 4; ++n)
                acc[m][n] = __builtin_amdgcn_mfma_f32_16x16x32_bf16(af[m], bf[n], acc[m][n], 0, 0, 0);
        __syncthreads();
        cur ^= 1;
    }

    // ---- cross-wave reduce: waves 2,3 write; waves 0,1 accumulate ----
    float* cb0 = (float*)&smem[0][0];                // 32 x CL
    float* cb1 = (float*)&smem[1][0];
    if (wid >= 2) {
        float* cb = (wid == 2) ? cb0 : cb1;
#pragma unroll
        for (int m = 0; m < 2; ++m)
#pragma unroll
            for (int n = 0; n < 4; ++n)
#pragma unroll
                for (int r = 0; r < 4; ++r)
                    cb[(m * 16 + l4 * 4 + r) * CL + n * 16 + l15] = acc[m][n][r];
    }
    __syncthreads();
    if (wid < 2) {
        float* cb = (wid == 0) ? cb0 : cb1;
#pragma unroll
        for (int m = 0; m < 2; ++m)
#pragma unroll
            for (int n = 0; n < 4; ++n)
#pragma unroll
                for (int r = 0; r < 4; ++r)
                    cb[(m * 16 + l4 * 4 + r) * CL + n * 16 + l15] += acc[m][n][r];
    }
    __syncthreads();

    // ---- epilogue: thread t -> row t>>3, cols (t&7)*8 .. +7 ----
    const int row = tid >> 3, c0 = (tid & 7) * 8;
    const int grow = m0 + row;
#pragma unroll
    for (int j = 0; j < 8; ++j) {
        const int gcol = n0 + c0 + j;
        float v = cb0[row * CL + c0 + j] + cb1[row * CL + c0 + j] + bias[gcol];
        if (ACT == 1) v = v >= 0.f ? v : 0.01f * v;
        else if (ACT == 2) v = fmaxf(v, 0.f);
        else if (ACT == 3) {
            const int t2 = grow % T_SEQ;
            const float mv = (t2 < CTXF || t2 == T_SEQ - 1) ? 1.0f : 0.0f;
            v = res[(size_t)grow * N + gcol] * mv + v * (1.0f - mv);
        }
        if (PE) v += pe15[((grow % T_SEQ) % PERIODN) * DMODEL + gcol];
        if (RES) v += res[(size_t)grow * N + gcol];
        if (OUTBF) ((ushort_t*)Cout)[(size_t)grow * N + gcol] = f2bf(v);
        else       ((float*)Cout)[(size_t)grow * N + gcol] = v;
    }
}

// ---------------------------------------------------------------------------
// LayerNorm: f32 in, bf16 out. One wave per row.
// ---------------------------------------------------------------------------
__global__ __launch_bounds__(256)
void ln_k(const float* __restrict__ X, const float* __restrict__ g,
          const float* __restrict__ b, ushort_t* __restrict__ Y) {
    const int wid = threadIdx.x >> 6, lane = threadIdx.x & 63;
    const int row = blockIdx.x * 4 + wid;
    const float* x = X + (size_t)row * DMODEL;
    float v[8], s = 0.f;
#pragma unroll
    for (int j = 0; j < 8; ++j) { v[j] = x[lane + 64 * j]; s += v[j]; }
#pragma unroll
    for (int o = 32; o; o >>= 1) s += __shfl_xor(s, o);
    const float mean = s * (1.0f / DMODEL);
    float vs = 0.f;
#pragma unroll
    for (int j = 0; j < 8; ++j) { float d = v[j] - mean; vs += d * d; }
#pragma unroll
    for (int o = 32; o; o >>= 1) vs += __shfl_xor(vs, o);
    const float inv = rsqrtf(vs * (1.0f / DMODEL) + 1e-5f);
    ushort_t* y = Y + (size_t)row * DMODEL;
#pragma unroll
    for (int j = 0; j < 8; ++j) {
        const int c = lane + 64 * j;
        y[c] = f2bf((v[j] - mean) * inv * g[c] + b[c]);
    }
}

// ---------------------------------------------------------------------------
// V-mean via linearity: mean_t(V) = mean_t(h) @ Wv + bv.
// vsum_k: partial row-sums of h. grid (NB, 8), 1024 thr, 192 rows/block.
// ---------------------------------------------------------------------------
__global__ __launch_bounds__(1024)
void vsum_k(const ushort_t* __restrict__ h, float* __restrict__ hp) {
    __shared__ float red[1024];
    const int b = blockIdx.x, ch = blockIdx.y;
    const int c = threadIdx.x & 511, half = threadIdx.x >> 9;
    const ushort_t* hb = h + (size_t)(b * T_SEQ + ch * 192) * DMODEL + c;
    float s = 0.f;
    for (int r = half; r < 192; r += 2) s += bf2f(hb[(size_t)r * DMODEL]);
    red[threadIdx.x] = s;
    __syncthreads();
    if (threadIdx.x < 512)
        hp[(b * 8 + ch) * 512 + threadIdx.x] = red[threadIdx.x] + red[threadIdx.x + 512];
}

// vdot_k: vm[b][col] = meanh . Wvt[col] + bv[col]. grid (NB, 4), 256 thr.
__global__ __launch_bounds__(256)
void vdot_k(const float* __restrict__ hp, const ushort_t* __restrict__ wvt,
            const float* __restrict__ bv, float* __restrict__ vm) {
    __shared__ float mh[512];
    __shared__ float red[256];
    const int b = blockIdx.x, seg = blockIdx.y;
    const int t = threadIdx.x;
    for (int c = t; c < 512; c += 256) {
        float s = 0.f;
#pragma unroll
        for (int ch = 0; ch < 8; ++ch) s += hp[(b * 8 + ch) * 512 + c];
        mh[c] = s * (1.0f / T_SEQ);
    }
    __syncthreads();
    const int col = seg * 128 + (t & 127);
    const int kh = (t >> 7) * 256;
    const ushort_t* w = wvt + (size_t)col * 512 + kh;
    float s = 0.f;
    for (int k = 0; k < 256; k += 8) {
        bf16x8 w8 = *(const bf16x8*)(w + k);
#pragma unroll
        for (int j = 0; j < 8; ++j) s += mh[kh + k + j] * (float)w8[j];
    }
    red[t] = s;
    __syncthreads();
    if (t < 128) vm[b * 512 + col] = red[t] + red[t + 128] + bv[col];
}

// ---------------------------------------------------------------------------
// MFMA flash attention + inactive-row fill. One WAVE per 16-row q-subtile.
// Tiles s<st: active attention; st<=s<st+ft: fill rows with vmean.
// Swapped operands: S^T = mfma(K,Q) -> q = lane&15; O^T = mfma(V^T, P).
// ---------------------------------------------------------------------------
#define KLD 72
#define VLD 36
__global__ __launch_bounds__(256)
void attn3_k(const ushort_t* __restrict__ qkv, const float* __restrict__ vm,
             ushort_t* __restrict__ attout,
             int lo, int hi, int nlow, int qhi0, int tl, int st, int ft) {
    __shared__ ushort_t klds_[4][32 * KLD];
    __shared__ ushort_t vlds_[4][64 * VLD];
    const int lane = threadIdx.x & 63, wid = threadIdx.x >> 6;
    const int s = blockIdx.x * 4 + wid;
    const int h = blockIdx.y, b = blockIdx.z;
    if (s >= st) {                                   // fill tiles
        const int f = s - st;
        if (f >= ft) return;
        const int r0 = nlow + 16 * f;
        const int rend = min(16, qhi0 - r0);
        const ushort_t ov = f2bf(vm[b * 512 + h * 64 + lane]);
        ushort_t* op = attout + (size_t)(b * T_SEQ + r0) * DMODEL + h * 64 + lane;
        for (int r = 0; r < rend; ++r) op[(size_t)r * DMODEL] = ov;
        return;
    }
    const int l15 = lane & 15, l4 = lane >> 4;

    int qb, qend;
    if (s < tl) { qb = 16 * s;                qend = nlow - 1; }
    else        { qb = qhi0 + 16 * (s - tl);  qend = T_SEQ - 1; }
    const int nr = qend - qb;

    ushort_t* klds = klds_[wid];
    ushort_t* vlds = vlds_[wid];
    const size_t rbase = (size_t)(b * T_SEQ) * 1536;
    const int q = qb + l15;

    const int qrow_r = min(q, T_SEQ - 1);
    const ushort_t* qptr = qkv + rbase + (size_t)qrow_r * 1536 + h * 64;
    bf16x8 bq[2];
#pragma unroll
    for (int kh = 0; kh < 2; ++kh) {
        bf16x4 lo4 = *(const bf16x4*)(qptr + kh * 32 + l4 * 4);
        bf16x4 hi4 = *(const bf16x4*)(qptr + kh * 32 + 16 + l4 * 4);
        bq[kh] = __builtin_shufflevector(lo4, hi4, 0, 1, 2, 3, 4, 5, 6, 7);
    }

    const int band0 = max(0, qb - THRW);
    const int band1 = min(T_SEQ - 1, qb + 15 + THRW);
    const int i1s = band0, i1e = min(band1, lo - 1);
    const int i2s = max(band0, hi), i2e = band1;

    f32x4 O[4] = {{0.f,0.f,0.f,0.f},{0.f,0.f,0.f,0.f},{0.f,0.f,0.f,0.f},{0.f,0.f,0.f,0.f}};
    float m = -3.0e38f, lsum = 0.f;

#pragma unroll 1
    for (int seg = 0; seg < 2; ++seg) {
        const int s0 = seg ? i2s : i1s, s1 = seg ? i2e : i1e;
#pragma unroll 1
        for (int c0 = s0; c0 <= s1; c0 += 32) {
#pragma unroll
            for (int i = 0; i < 4; ++i) {
                const int idx = i * 64 + lane;
                const int row = idx >> 3, c = (idx & 7) * 8;
                const int kr = min(c0 + row, T_SEQ - 1);
                const uint4 kv = *(const uint4*)(qkv + rbase + (size_t)kr * 1536 + 512 + h * 64 + c);
                *(uint4*)&klds[row * KLD + c] = kv;
                const uint4 vv = *(const uint4*)(qkv + rbase + (size_t)kr * 1536 + 1024 + h * 64 + c);
                const ushort_t* vp = (const ushort_t*)&vv;
#pragma unroll
                for (int d = 0; d < 8; ++d) vlds[(c + d) * VLD + row] = vp[d];
            }
            f32x4 sacc[2];
            __builtin_amdgcn_s_setprio(1);
#pragma unroll
            for (int ks = 0; ks < 2; ++ks) {
                f32x4 a = {0.f, 0.f, 0.f, 0.f};
#pragma unroll
                for (int kh = 0; kh < 2; ++kh) {
                    const ushort_t* kp = &klds[(16 * ks + l15) * KLD + kh * 32];
                    bf16x4 lo4 = *(const bf16x4*)(kp + l4 * 4);
                    bf16x4 hi4 = *(const bf16x4*)(kp + 16 + l4 * 4);
                    bf16x8 ak = __builtin_shufflevector(lo4, hi4, 0, 1, 2, 3, 4, 5, 6, 7);
                    a = __builtin_amdgcn_mfma_f32_16x16x32_bf16(ak, bq[kh], a, 0, 0, 0);
                }
                sacc[ks] = a;
            }
            __builtin_amdgcn_s_setprio(0);
            float sv[8];
            bool vld[8];
            float cm = -3.0e38f;
#pragma unroll
            for (int ks = 0; ks < 2; ++ks)
#pragma unroll
                for (int r = 0; r < 4; ++r) {
                    const int key = c0 + 16 * ks + 4 * l4 + r;
                    const int dist = (q > key) ? (q - key) : (key - q);
                    const bool v = (dist <= THRW) && (key < lo || key >= hi) && (key < T_SEQ);
                    const int ii = ks * 4 + r;
                    sv[ii] = sacc[ks][r] * 0.125f - (float)(dist / PERIODN);
                    vld[ii] = v;
                    cm = fmaxf(cm, v ? sv[ii] : -3.0e38f);
                }
            cm = fmaxf(cm, __shfl_xor(cm, 16));
            cm = fmaxf(cm, __shfl_xor(cm, 32));
            const float mnew = fmaxf(m, cm);
            const float sc = __expf(m - mnew);
            m = mnew;
            float p[8], psum = 0.f;
#pragma unroll
            for (int ii = 0; ii < 8; ++ii) {
                p[ii] = vld[ii] ? __expf(sv[ii] - mnew) : 0.f;
                psum += p[ii];
            }
            psum += __shfl_xor(psum, 16);
            psum += __shfl_xor(psum, 32);
            lsum = lsum * sc + psum;
#pragma unroll
            for (int ds = 0; ds < 4; ++ds) O[ds] *= sc;
            bf16x8 pb;
#pragma unroll
            for (int ii = 0; ii < 8; ++ii) pb[ii] = (__bf16)p[ii];
            __builtin_amdgcn_s_setprio(1);
#pragma unroll
            for (int ds = 0; ds < 4; ++ds) {
                const ushort_t* vp2 = &vlds[(16 * ds + l15) * VLD];
                bf16x4 lo4 = *(const bf16x4*)(vp2 + 4 * l4);
                bf16x4 hi4 = *(const bf16x4*)(vp2 + 16 + 4 * l4);
                bf16x8 av = __builtin_shufflevector(lo4, hi4, 0, 1, 2, 3, 4, 5, 6, 7);
                O[ds] = __builtin_amdgcn_mfma_f32_16x16x32_bf16(av, pb, O[ds], 0, 0, 0);
            }
            __builtin_amdgcn_s_setprio(0);
        }
    }
    if (l15 <= nr) {
        const float inv = 1.0f / lsum;
        ushort_t* op = attout + (size_t)(b * T_SEQ + qb + l15) * DMODEL + h * 64;
#pragma unroll
        for (int ds = 0; ds < 4; ++ds)
#pragma unroll
            for (int r = 0; r < 4; ++r)
                op[16 * ds + 4 * l4 + r] = f2bf(O[ds][r] * inv);
    }
}

// ---------------------------------------------------------------------------
extern "C" void kernel_launch(void* const* d_in, const int* in_sizes, int n_in,
                              void* d_out, int out_size, void* d_ws, size_t ws_size,
                              hipStream_t stream) {
    const float* motion = (const float*)d_in[0];
    const float* traj   = (const float*)d_in[1];
    const float* me_w1  = (const float*)d_in[2];
    const float* me_b1  = (const float*)d_in[3];
    const float* me_w2  = (const float*)d_in[4];
    const float* me_b2  = (const float*)d_in[5];
    const float* wq = (const float*)d_in[6];
    const float* bq = (const float*)d_in[7];
    const float* wk = (const float*)d_in[8];
    const float* bk = (const float*)d_in[9];
    const float* wv = (const float*)d_in[10];
    const float* bv = (const float*)d_in[11];
    const float* wo = (const float*)d_in[12];
    const float* bo = (const float*)d_in[13];
    const float* ln1_g = (const float*)d_in[14];
    const float* ln1_b = (const float*)d_in[15];
    const float* ffn_w1 = (const float*)d_in[16];
    const float* ffn_b1 = (const float*)d_in[17];
    const float* ffn_w2 = (const float*)d_in[18];
    const float* ffn_b2 = (const float*)d_in[19];
    const float* ln2_g = (const float*)d_in[20];
    const float* ln2_b = (const float*)d_in[21];
    const float* fln_g = (const float*)d_in[22];
    const float* fln_b = (const float*)d_in[23];
    const float* dec_w1 = (const float*)d_in[24];
    const float* dec_b1 = (const float*)d_in[25];
    const float* dec_w2 = (const float*)d_in[26];
    const float* dec_b2 = (const float*)d_in[27];

    float* out = (float*)d_out;
    float* mask_out = out + (size_t)MROWS * DMOTION;

    char* base = (char*)d_ws;
    auto alloc = [&](size_t bytes) { char* p = base; base += (bytes + 255) & ~(size_t)255; return p; };

    ushort_t* qkvt  = (ushort_t*)alloc((size_t)NLAYERS * 1536 * 512 * 2);
    ushort_t* wot   = (ushort_t*)alloc((size_t)NLAYERS * 512 * 512 * 2);
    ushort_t* ffn1t = (ushort_t*)alloc((size_t)NLAYERS * 2048 * 512 * 2);
    ushort_t* ffn2t = (ushort_t*)alloc((size_t)NLAYERS * 512 * 2048 * 2);
    ushort_t* mew1t = (ushort_t*)alloc((size_t)512 * KIN * 2);
    ushort_t* mew2t = (ushort_t*)alloc((size_t)512 * 512 * 2);
    ushort_t* dec1t = (ushort_t*)alloc((size_t)512 * 512 * 2);
    ushort_t* dec2t = (ushort_t*)alloc((size_t)256 * 512 * 2);
    float*    bqkv  = (float*)alloc((size_t)NLAYERS * 1536 * 4);
    float*    pe15  = (float*)alloc((size_t)PERIODN * DMODEL * 4);
    float*    hp    = (float*)alloc((size_t)NB * 8 * 512 * 4);
    float*    vm    = (float*)alloc((size_t)NB * 512 * 4);
    ushort_t* hin   = (ushort_t*)alloc((size_t)MROWS * KIN * 2);
    float*    x     = (float*)alloc((size_t)MROWS * DMODEL * 4);
    ushort_t* h     = (ushort_t*)alloc((size_t)MROWS * DMODEL * 2);
    ushort_t* qkv   = (ushort_t*)alloc((size_t)MROWS * 1536 * 2);
    ushort_t* ff    = (ushort_t*)alloc((size_t)MROWS * DFF * 2);

    const dim3 blk(256);
    pe_k<<<(PERIODN * DMODEL + 255) / 256, blk, 0, stream>>>(pe15);
    build_k<<<(MROWS * KIN + 255) / 256, blk, 0, stream>>>(motion, traj, hin, mask_out);

    tconv_qkv_k<<<dim3(16, 16, 18), blk, 0, stream>>>(wq, wk, wv, qkvt);
    tconv_k<<<dim3(16, 16, 6), blk, 0, stream>>>(wo, 512 * 512, wot, 512 * 512, 512, 512, 512);
    tconv_k<<<dim3(64, 16, 6), blk, 0, stream>>>(ffn_w1, 512 * 2048, ffn1t, 2048 * 512, 512, 2048, 512);
    tconv_k<<<dim3(16, 64, 6), blk, 0, stream>>>(ffn_w2, 2048 * 512, ffn2t, 512 * 2048, 2048, 512, 2048);
    tconv_k<<<dim3(16, 12, 1), blk, 0, stream>>>(me_w1, 0, mew1t, 0, 262, 512, KIN);
    tconv_k<<<dim3(16, 16, 1), blk, 0, stream>>>(me_w2, 0, mew2t, 0, 512, 512, 512);
    tconv_k<<<dim3(16, 16, 1), blk, 0, stream>>>(dec_w1, 0, dec1t, 0, 512, 512, 512);
    tconv_k<<<dim3(8, 16, 1),  blk, 0, stream>>>(dec_w2, 0, dec2t, 0, 512, 256, 512);
    bcat_k<<<(NLAYERS * 1536 + 255) / 256, blk, 0, stream>>>(bq, bk, bv, bqkv);

    const dim3 gs512(8, 96), gs1536(24, 96), gsff(32, 96), gs256(4, 96);

    // motion encoder
    qgemm_k<1, false, false, true ><<<gs512, blk, 0, stream>>>(hin, KIN, mew1t, me_b1, nullptr, nullptr, h, 512);
    qgemm_k<1, false, true,  false><<<gs512, blk, 0, stream>>>(h, 512, mew2t, me_b2, nullptr, pe15, x, 512);

    for (int i = 0; i < NLAYERS; ++i) {
        const int lo = CTXF + THRW * i;
        const int hi = (T_SEQ - 1) - THRW * i;
        int qlow_end = lo + 127;
        int qhi0 = hi - 128;
        int nlow, ninact;
        if (qhi0 <= qlow_end + 1) {
            nlow = T_SEQ; qhi0 = T_SEQ; ninact = 0;
        } else {
            nlow = qlow_end + 1;
            ninact = qhi0 - nlow;
        }
        const int tl2 = (nlow + 15) / 16;
        const int th2 = (T_SEQ - qhi0 + 15) / 16;
        const int st  = tl2 + th2;
        const int ft  = (ninact + 15) / 16;

        ln_k<<<MROWS / 4, blk, 0, stream>>>(x, ln1_g + i * 512, ln1_b + i * 512, h);
        qgemm_k<0, false, false, true><<<gs1536, blk, 0, stream>>>(h, 512, qkvt + (size_t)i * 1536 * 512, bqkv + i * 1536, nullptr, nullptr, qkv, 1536);
        if (ninact > 0) {
            vsum_k<<<dim3(NB, 8), dim3(1024), 0, stream>>>(h, hp);
            vdot_k<<<dim3(NB, 4), blk, 0, stream>>>(hp, qkvt + (size_t)i * 1536 * 512 + (size_t)1024 * 512, bqkv + i * 1536 + 1024, vm);
        }
        attn3_k<<<dim3((st + ft + 3) / 4, NHEADS, NB), blk, 0, stream>>>(qkv, vm, h, lo, hi, nlow, qhi0, tl2, st, ft);
        qgemm_k<0, true, false, false><<<gs512, blk, 0, stream>>>(h, 512, wot + (size_t)i * 512 * 512, bo + i * 512, x, nullptr, x, 512);
        ln_k<<<MROWS / 4, blk, 0, stream>>>(x, ln2_g + i * 512, ln2_b + i * 512, h);
        qgemm_k<2, false, false, true><<<gsff, blk, 0, stream>>>(h, 512, ffn1t + (size_t)i * 2048 * 512, ffn_b1 + i * 2048, nullptr, nullptr, ff, 2048);
        qgemm_k<0, true, false, false><<<gs512, blk, 0, stream>>>(ff, 2048, ffn2t + (size_t)i * 512 * 2048, ffn_b2 + i * 512, x, nullptr, x, 512);
    }

    // decoder: dec1 (leaky) -> dec2 fused with final blend (ACT=3, res=motion)
    ln_k<<<MROWS / 4, blk, 0, stream>>>(x, fln_g, fln_b, h);
    qgemm_k<1, false, false, true ><<<gs512, blk, 0, stream>>>(h, 512, dec1t, dec_b1, nullptr, nullptr, ff, 512);
    qgemm_k<3, false, false, false><<<gs256, blk, 0, stream>>>(ff, 512, dec2t, dec_b2, motion, nullptr, out, 256);
}

// Round 11
// 831.192 us; speedup vs baseline: 1.0249x; 1.0249x over previous
//
#include <hip/hip_runtime.h>
#include <math.h>

typedef unsigned short ushort_t;
typedef unsigned int uint_t;
typedef __bf16 bf16x4 __attribute__((ext_vector_type(4)));
typedef __bf16 bf16x8 __attribute__((ext_vector_type(8)));
typedef float f32x4 __attribute__((ext_vector_type(4)));

#define T_SEQ   1536
#define NB      2
#define MROWS   3072
#define DMODEL  512
#define NHEADS  8
#define DHEAD   64
#define DFF     2048
#define DMOTION 256
#define NLAYERS 6
#define PERIODN 15
#define CTXF    10
#define THRW    128
#define KIN     384           // 262 zero-padded to multiple of 128

__device__ __forceinline__ float bf2f(ushort_t u) { return __uint_as_float((uint_t)u << 16); }
__device__ __forceinline__ ushort_t f2bf(float f) {
    uint_t x = __float_as_uint(f);
    return (ushort_t)((x + 0x7fffu + ((x >> 16) & 1u)) >> 16);   // RNE
}

__device__ __forceinline__ void gl2lds(const ushort_t* g, ushort_t* l) {
    __builtin_amdgcn_global_load_lds((const __attribute__((address_space(1))) void*)g,
                                     (__attribute__((address_space(3))) void*)l, 16, 0, 0);
}

// ---------------------------------------------------------------------------
__global__ __launch_bounds__(256) void pe_k(float* __restrict__ pe) {
    int idx = blockIdx.x * 256 + threadIdx.x;
    if (idx >= PERIODN * DMODEL) return;
    int p = idx / DMODEL, c = idx % DMODEL;
    int j = (c < DMODEL / 2) ? c : (c - DMODEL / 2);
    float div = __expf(-logf(10000.0f) * (2.0f * (float)j) / (float)DMODEL);
    float ang = (float)p * div;
    pe[idx] = (c < DMODEL / 2) ? sinf(ang) : cosf(ang);
}

// ---------------------------------------------------------------------------
__global__ __launch_bounds__(256) void build_k(const float* __restrict__ motion,
                                               const float* __restrict__ traj,
                                               ushort_t* __restrict__ hin,
                                               float* __restrict__ mask_out) {
    int idx = blockIdx.x * 256 + threadIdx.x;
    if (idx >= MROWS * KIN) return;
    int row = idx / KIN, c = idx % KIN;
    int t = row % T_SEQ;
    float mv = (t < CTXF || t == T_SEQ - 1) ? 1.0f : 0.0f;
    float val;
    if (c < DMOTION)            val = motion[(size_t)row * DMOTION + c] * mv;
    else if (c < DMOTION + 5)   val = traj[(size_t)row * 5 + (c - DMOTION)];
    else if (c == DMOTION + 5)  val = mv;
    else                        val = 0.0f;
    hin[idx] = f2bf(val);
    if (c == 0) mask_out[row] = mv;
}

// ---------------------------------------------------------------------------
__global__ __launch_bounds__(256)
void tconv_k(const float* __restrict__ src, size_t sstride,
             ushort_t* __restrict__ dst, size_t dstride,
             int K, int N, int Kpad) {
    __shared__ float t[32][33];
    src += (size_t)blockIdx.z * sstride;
    dst += (size_t)blockIdx.z * dstride;
    const int kb = blockIdx.y * 32, nb = blockIdx.x * 32;
    const int tx = threadIdx.x & 31, ty = threadIdx.x >> 5;
#pragma unroll
    for (int i = 0; i < 4; ++i) {
        int k = kb + ty + i * 8, n = nb + tx;
        t[ty + i * 8][tx] = (k < K && n < N) ? src[(size_t)k * N + n] : 0.0f;
    }
    __syncthreads();
#pragma unroll
    for (int i = 0; i < 4; ++i) {
        int n = nb + ty + i * 8, kk = kb + tx;
        if (n < N && kk < Kpad) dst[(size_t)n * Kpad + kk] = f2bf(t[tx][ty + i * 8]);
    }
}

__global__ __launch_bounds__(256)
void tconv_qkv_k(const float* __restrict__ wq, const float* __restrict__ wk,
                 const float* __restrict__ wv, ushort_t* __restrict__ qkvt) {
    __shared__ float t[32][33];
    const int z = blockIdx.z, s = z % 3, l = z / 3;
    const float* src = (s == 0 ? wq : s == 1 ? wk : wv) + (size_t)l * DMODEL * DMODEL;
    ushort_t* dst = qkvt + (size_t)z * DMODEL * DMODEL;
    const int kb = blockIdx.y * 32, nb = blockIdx.x * 32;
    const int tx = threadIdx.x & 31, ty = threadIdx.x >> 5;
#pragma unroll
    for (int i = 0; i < 4; ++i)
        t[ty + i * 8][tx] = src[(size_t)(kb + ty + i * 8) * DMODEL + nb + tx];
    __syncthreads();
#pragma unroll
    for (int i = 0; i < 4; ++i)
        dst[(size_t)(nb + ty + i * 8) * DMODEL + kb + tx] = f2bf(t[tx][ty + i * 8]);
}

__global__ __launch_bounds__(256)
void bcat_k(const float* __restrict__ bq, const float* __restrict__ bk,
            const float* __restrict__ bv, float* __restrict__ bqkv) {
    int idx = blockIdx.x * 256 + threadIdx.x;
    if (idx >= NLAYERS * 3 * DMODEL) return;
    int l = idx / (3 * DMODEL), n = idx % (3 * DMODEL);
    int s = n >> 9, c = n & 511;
    const float* b = (s == 0 ? bq : s == 1 ? bk : bv);
    bqkv[idx] = b[l * DMODEL + c];
}

// ---------------------------------------------------------------------------
// Full-M split-K bf16 MFMA GEMM (round-9 proven). ACT: 0 none, 1 leaky,
// 2 relu, 3 final-blend (v = res*mv + v*(1-mv)).
// ---------------------------------------------------------------------------
#define CL  68
template <int ACT, bool RES, bool PE, bool OUTBF>
__global__ __launch_bounds__(256)
void qgemm_k(const ushort_t* __restrict__ A, int K,
             const ushort_t* __restrict__ Wt,
             const float* __restrict__ bias,
             const float* __restrict__ res,
             const float* __restrict__ pe15,
             void* __restrict__ Cout, int N) {
    __shared__ ushort_t smem[2][(32 + 64) * 128];
    const int tid = threadIdx.x;
    const int lane = tid & 63, wid = tid >> 6;
    const int m0 = blockIdx.y * 32, n0 = blockIdx.x * 64;
    const int l4 = lane >> 4, l15 = lane & 15;
    const int lrow = lane >> 4;
    const int lu   = lane & 15;

    f32x4 acc[2][4];
#pragma unroll
    for (int m = 0; m < 2; ++m)
#pragma unroll
        for (int n = 0; n < 4; ++n) acc[m][n] = (f32x4){0.f, 0.f, 0.f, 0.f};

    const int niter = K >> 7;

    auto stage = [&](int buf, int k0) {
        ushort_t* dst = &smem[buf][0];
#pragma unroll
        for (int j = 0; j < 6; ++j) {
            const int inst = wid * 6 + j;
            if (inst < 8) {
                const int row = inst * 4 + lrow;
                const int u = lu ^ (row & 15);
                gl2lds(A + (size_t)(m0 + row) * K + k0 + u * 8, dst + inst * 512);
            } else {
                const int bi = inst - 8;
                const int row = bi * 4 + lrow;
                const int u = lu ^ (row & 15);
                gl2lds(Wt + (size_t)(n0 + row) * K + k0 + u * 8,
                       dst + 32 * 128 + bi * 512);
            }
        }
    };

    const int kbyte = wid * 64;
    auto rdfrag = [&](const ushort_t* t, int row) -> bf16x8 {
        const int off0 = kbyte + l4 * 8;
        const int off1 = kbyte + 32 + l4 * 8;
        const int a0 = row * 256 + (((off0 & ~15) ^ ((row & 15) << 4)) | (off0 & 15));
        const int a1 = row * 256 + (((off1 & ~15) ^ ((row & 15) << 4)) | (off1 & 15));
        bf16x4 lo = *(const bf16x4*)((const char*)t + a0);
        bf16x4 hi = *(const bf16x4*)((const char*)t + a1);
        return __builtin_shufflevector(lo, hi, 0, 1, 2, 3, 4, 5, 6, 7);
    };

    stage(0, 0);
    __syncthreads();
    int cur = 0;
    for (int t = 0; t < niter; ++t) {
        if (t + 1 < niter) stage(cur ^ 1, (t + 1) << 7);
        const ushort_t* As = &smem[cur][0];
        const ushort_t* Bs = &smem[cur][32 * 128];
        bf16x8 af[2], bf[4];
#pragma unroll
        for (int m = 0; m < 2; ++m) af[m] = rdfrag(As, m * 16 + l15);
#pragma unroll
        for (int n = 0; n < 4; ++n) bf[n] = rdfrag(Bs, n * 16 + l15);
#pragma unroll
        for (int m = 0; m < 2; ++m)
#pragma unroll
            for (int n = 0; n < 4; ++n)
                acc[m][n] = __builtin_amdgcn_mfma_f32_16x16x32_bf16(af[m], bf[n], acc[m][n], 0, 0, 0);
        __syncthreads();
        cur ^= 1;
    }

    float* cb0 = (float*)&smem[0][0];
    float* cb1 = (float*)&smem[1][0];
    if (wid >= 2) {
        float* cb = (wid == 2) ? cb0 : cb1;
#pragma unroll
        for (int m = 0; m < 2; ++m)
#pragma unroll
            for (int n = 0; n < 4; ++n)
#pragma unroll
                for (int r = 0; r < 4; ++r)
                    cb[(m * 16 + l4 * 4 + r) * CL + n * 16 + l15] = acc[m][n][r];
    }
    __syncthreads();
    if (wid < 2) {
        float* cb = (wid == 0) ? cb0 : cb1;
#pragma unroll
        for (int m = 0; m < 2; ++m)
#pragma unroll
            for (int n = 0; n < 4; ++n)
#pragma unroll
                for (int r = 0; r < 4; ++r)
                    cb[(m * 16 + l4 * 4 + r) * CL + n * 16 + l15] += acc[m][n][r];
    }
    __syncthreads();

    const int row = tid >> 3, c0 = (tid & 7) * 8;
    const int grow = m0 + row;
#pragma unroll
    for (int j = 0; j < 8; ++j) {
        const int gcol = n0 + c0 + j;
        float v = cb0[row * CL + c0 + j] + cb1[row * CL + c0 + j] + bias[gcol];
        if (ACT == 1) v = v >= 0.f ? v : 0.01f * v;
        else if (ACT == 2) v = fmaxf(v, 0.f);
        else if (ACT == 3) {
            const int t2 = grow % T_SEQ;
            const float mv = (t2 < CTXF || t2 == T_SEQ - 1) ? 1.0f : 0.0f;
            v = res[(size_t)grow * N + gcol] * mv + v * (1.0f - mv);
        }
        if (PE) v += pe15[((grow % T_SEQ) % PERIODN) * DMODEL + gcol];
        if (RES) v += res[(size_t)grow * N + gcol];
        if (OUTBF) ((ushort_t*)Cout)[(size_t)grow * N + gcol] = f2bf(v);
        else       ((float*)Cout)[(size_t)grow * N + gcol] = v;
    }
}

// ---------------------------------------------------------------------------
// Packed-row GEMM over two row-intervals per batch (K fixed = 512, lda = 512).
// Packed row r (per batch): global t = r < len1 ? r : start2 + (r - len1).
// grid.y = 2*tpb (tpb tiles per batch). Rows r >= nact: reads clamped,
// writes skipped. RES adds f32 res[grow*ldc+col]. OUTBF selects C dtype.
// ---------------------------------------------------------------------------
template <bool RES, bool OUTBF>
__global__ __launch_bounds__(256)
void pgemm_k(const ushort_t* __restrict__ A,
             const ushort_t* __restrict__ Wt,
             const float* __restrict__ bias,
             const float* __restrict__ res,
             void* __restrict__ Cout, int ldc,
             int tpb, int len1, int start2, int nact) {
    __shared__ ushort_t smem[2][(32 + 64) * 128];
    const int tid = threadIdx.x;
    const int lane = tid & 63, wid = tid >> 6;
    const int ty = blockIdx.y;
    const int bb = (ty >= tpb) ? 1 : 0;
    const int t32 = (ty - bb * tpb) * 32;
    const int n0 = blockIdx.x * 64;
    const int l4 = lane >> 4, l15 = lane & 15;
    const int lrow = lane >> 4;
    const int lu   = lane & 15;

    auto maprow = [&](int pr) -> size_t {          // pr in [0,32), clamped read
        int r = t32 + pr;
        r = min(r, nact - 1);
        int tt = (r < len1) ? r : (start2 + (r - len1));
        return (size_t)(bb * T_SEQ + tt);
    };

    f32x4 acc[2][4];
#pragma unroll
    for (int m = 0; m < 2; ++m)
#pragma unroll
        for (int n = 0; n < 4; ++n) acc[m][n] = (f32x4){0.f, 0.f, 0.f, 0.f};

    auto stage = [&](int buf, int k0) {
        ushort_t* dst = &smem[buf][0];
#pragma unroll
        for (int j = 0; j < 6; ++j) {
            const int inst = wid * 6 + j;
            if (inst < 8) {
                const int row = inst * 4 + lrow;          // packed row ordinal
                const int u = lu ^ (row & 15);
                gl2lds(A + maprow(row) * 512 + k0 + u * 8, dst + inst * 512);
            } else {
                const int bi = inst - 8;
                const int row = bi * 4 + lrow;
                const int u = lu ^ (row & 15);
                gl2lds(Wt + (size_t)(n0 + row) * 512 + k0 + u * 8,
                       dst + 32 * 128 + bi * 512);
            }
        }
    };

    const int kbyte = wid * 64;
    auto rdfrag = [&](const ushort_t* t, int row) -> bf16x8 {
        const int off0 = kbyte + l4 * 8;
        const int off1 = kbyte + 32 + l4 * 8;
        const int a0 = row * 256 + (((off0 & ~15) ^ ((row & 15) << 4)) | (off0 & 15));
        const int a1 = row * 256 + (((off1 & ~15) ^ ((row & 15) << 4)) | (off1 & 15));
        bf16x4 lo = *(const bf16x4*)((const char*)t + a0);
        bf16x4 hi = *(const bf16x4*)((const char*)t + a1);
        return __builtin_shufflevector(lo, hi, 0, 1, 2, 3, 4, 5, 6, 7);
    };

    stage(0, 0);
    __syncthreads();
    int cur = 0;
    for (int t = 0; t < 4; ++t) {                      // K = 512, BK = 128
        if (t + 1 < 4) stage(cur ^ 1, (t + 1) << 7);
        const ushort_t* As = &smem[cur][0];
        const ushort_t* Bs = &smem[cur][32 * 128];
        bf16x8 af[2], bf[4];
#pragma unroll
        for (int m = 0; m < 2; ++m) af[m] = rdfrag(As, m * 16 + l15);
#pragma unroll
        for (int n = 0; n < 4; ++n) bf[n] = rdfrag(Bs, n * 16 + l15);
#pragma unroll
        for (int m = 0; m < 2; ++m)
#pragma unroll
            for (int n = 0; n < 4; ++n)
                acc[m][n] = __builtin_amdgcn_mfma_f32_16x16x32_bf16(af[m], bf[n], acc[m][n], 0, 0, 0);
        __syncthreads();
        cur ^= 1;
    }

    float* cb0 = (float*)&smem[0][0];
    float* cb1 = (float*)&smem[1][0];
    if (wid >= 2) {
        float* cb = (wid == 2) ? cb0 : cb1;
#pragma unroll
        for (int m = 0; m < 2; ++m)
#pragma unroll
            for (int n = 0; n < 4; ++n)
#pragma unroll
                for (int r = 0; r < 4; ++r)
                    cb[(m * 16 + l4 * 4 + r) * CL + n * 16 + l15] = acc[m][n][r];
    }
    __syncthreads();
    if (wid < 2) {
        float* cb = (wid == 0) ? cb0 : cb1;
#pragma unroll
        for (int m = 0; m < 2; ++m)
#pragma unroll
            for (int n = 0; n < 4; ++n)
#pragma unroll
                for (int r = 0; r < 4; ++r)
                    cb[(m * 16 + l4 * 4 + r) * CL + n * 16 + l15] += acc[m][n][r];
    }
    __syncthreads();

    const int row = tid >> 3, c0 = (tid & 7) * 8;
    const int pr = t32 + row;
    if (pr >= nact) return;
    const int tt = (pr < len1) ? pr : (start2 + (pr - len1));
    const size_t grow = (size_t)(bb * T_SEQ + tt);
#pragma unroll
    for (int j = 0; j < 8; ++j) {
        const int gcol = n0 + c0 + j;
        float v = cb0[row * CL + c0 + j] + cb1[row * CL + c0 + j] + bias[gcol];
        if (RES) v += res[grow * ldc + gcol];
        if (OUTBF) ((ushort_t*)Cout)[grow * ldc + gcol] = f2bf(v);
        else       ((float*)Cout)[grow * ldc + gcol] = v;
    }
}

// ---------------------------------------------------------------------------
// LayerNorm: f32 in, bf16 out. One wave per row.
// ---------------------------------------------------------------------------
__global__ __launch_bounds__(256)
void ln_k(const float* __restrict__ X, const float* __restrict__ g,
          const float* __restrict__ b, ushort_t* __restrict__ Y) {
    const int wid = threadIdx.x >> 6, lane = threadIdx.x & 63;
    const int row = blockIdx.x * 4 + wid;
    const float* x = X + (size_t)row * DMODEL;
    float v[8], s = 0.f;
#pragma unroll
    for (int j = 0; j < 8; ++j) { v[j] = x[lane + 64 * j]; s += v[j]; }
#pragma unroll
    for (int o = 32; o; o >>= 1) s += __shfl_xor(s, o);
    const float mean = s * (1.0f / DMODEL);
    float vs = 0.f;
#pragma unroll
    for (int j = 0; j < 8; ++j) { float d = v[j] - mean; vs += d * d; }
#pragma unroll
    for (int o = 32; o; o >>= 1) vs += __shfl_xor(vs, o);
    const float inv = rsqrtf(vs * (1.0f / DMODEL) + 1e-5f);
    ushort_t* y = Y + (size_t)row * DMODEL;
#pragma unroll
    for (int j = 0; j < 8; ++j) {
        const int c = lane + 64 * j;
        y[c] = f2bf((v[j] - mean) * inv * g[c] + b[c]);
    }
}

// ---------------------------------------------------------------------------
// V-mean via linearity: vm = mean_t(h) @ Wv + bv (h = LN1 output, all rows).
// vsum_k: vectorized partial row-sums. grid (NB, 8), 1024 thr.
// ---------------------------------------------------------------------------
__global__ __launch_bounds__(1024)
void vsum_k(const ushort_t* __restrict__ h, float* __restrict__ hp) {
    __shared__ float red[16][512];
    const int b = blockIdx.x, ch = blockIdx.y;
    const int rg = threadIdx.x >> 6;            // 0..15 row groups
    const int c8 = (threadIdx.x & 63) * 8;      // col block
    const ushort_t* hb = h + (size_t)(b * T_SEQ + ch * 192) * DMODEL + c8;
    float a[8] = {};
    for (int r = rg; r < 192; r += 16) {
        bf16x8 v = *(const bf16x8*)(hb + (size_t)r * DMODEL);
#pragma unroll
        for (int j = 0; j < 8; ++j) a[j] += (float)v[j];
    }
#pragma unroll
    for (int j = 0; j < 8; ++j) red[rg][c8 + j] = a[j];
    __syncthreads();
    if (threadIdx.x < 512) {
        float s = 0.f;
#pragma unroll
        for (int gi = 0; gi < 16; ++gi) s += red[gi][threadIdx.x];
        hp[(b * 8 + ch) * 512 + threadIdx.x] = s;
    }
}

// vdot_k: vm[b][col] = mean(h) . Wvt[col] + bv[col]. grid (NB, 4), 256 thr.
__global__ __launch_bounds__(256)
void vdot_k(const float* __restrict__ hp, const ushort_t* __restrict__ wvt,
            const float* __restrict__ bv, float* __restrict__ vm) {
    __shared__ float mh[512];
    __shared__ float red[256];
    const int b = blockIdx.x, seg = blockIdx.y;
    const int t = threadIdx.x;
    for (int c = t; c < 512; c += 256) {
        float s = 0.f;
#pragma unroll
        for (int ch = 0; ch < 8; ++ch) s += hp[(b * 8 + ch) * 512 + c];
        mh[c] = s * (1.0f / T_SEQ);
    }
    __syncthreads();
    const int col = seg * 128 + (t & 127);
    const int kh = (t >> 7) * 256;
    const ushort_t* w = wvt + (size_t)col * 512 + kh;
    float s = 0.f;
    for (int k = 0; k < 256; k += 8) {
        bf16x8 w8 = *(const bf16x8*)(w + k);
#pragma unroll
        for (int j = 0; j < 8; ++j) s += mh[kh + k + j] * (float)w8[j];
    }
    red[t] = s;
    __syncthreads();
    if (t < 128) vm[b * 512 + col] = red[t] + red[t + 128] + bv[col];
}

// gemv_k: vout[b][col] = vin[b] . wt[col] + bias[col]. grid (NB, 4), 256 thr.
__global__ __launch_bounds__(256)
void gemv_k(const float* __restrict__ vin, const ushort_t* __restrict__ wt,
            const float* __restrict__ bias, float* __restrict__ vout) {
    __shared__ float mh[512];
    __shared__ float red[256];
    const int b = blockIdx.x, seg = blockIdx.y;
    const int t = threadIdx.x;
    for (int c = t; c < 512; c += 256) mh[c] = vin[b * 512 + c];
    __syncthreads();
    const int col = seg * 128 + (t & 127);
    const int kh = (t >> 7) * 256;
    const ushort_t* w = wt + (size_t)col * 512 + kh;
    float s = 0.f;
    for (int k = 0; k < 256; k += 8) {
        bf16x8 w8 = *(const bf16x8*)(w + k);
#pragma unroll
        for (int j = 0; j < 8; ++j) s += mh[kh + k + j] * (float)w8[j];
    }
    red[t] = s;
    __syncthreads();
    if (t < 128) vout[b * 512 + col] = red[t] + red[t + 128] + bias[col];
}

// xadd_k: x[inactive row] += vmo[b]. grid (ninact, NB), 256 thr.
__global__ __launch_bounds__(256)
void xadd_k(const float* __restrict__ vmo, float* __restrict__ x, int q0) {
    const int row = q0 + blockIdx.x, b = blockIdx.y;
    float* xr = x + (size_t)(b * T_SEQ + row) * DMODEL;
    const float* vb = vmo + b * 512;
    xr[threadIdx.x]       += vb[threadIdx.x];
    xr[threadIdx.x + 256] += vb[threadIdx.x + 256];
}

// ---------------------------------------------------------------------------
// MFMA flash attention (round-9 proven). One WAVE per 16-row q-subtile.
// Swapped operands: S^T = mfma(K,Q) -> q = lane&15; O^T = mfma(V^T, P).
// ---------------------------------------------------------------------------
#define KLD 72
#define VLD 36
__global__ __launch_bounds__(256)
void attn3_k(const ushort_t* __restrict__ qkv, ushort_t* __restrict__ attout,
             int lo, int hi, int nlow, int qhi0, int tl, int st) {
    __shared__ ushort_t klds_[4][32 * KLD];
    __shared__ ushort_t vlds_[4][64 * VLD];
    const int lane = threadIdx.x & 63, wid = threadIdx.x >> 6;
    const int s = blockIdx.x * 4 + wid;
    if (s >= st) return;
    const int h = blockIdx.y, b = blockIdx.z;
    const int l15 = lane & 15, l4 = lane >> 4;

    int qb, qend;
    if (s < tl) { qb = 16 * s;                qend = nlow - 1; }
    else        { qb = qhi0 + 16 * (s - tl);  qend = T_SEQ - 1; }
    const int nr = qend - qb;

    ushort_t* klds = klds_[wid];
    ushort_t* vlds = vlds_[wid];
    const size_t rbase = (size_t)(b * T_SEQ) * 1536;
    const int q = qb + l15;

    const int qrow_r = min(q, T_SEQ - 1);
    const ushort_t* qptr = qkv + rbase + (size_t)qrow_r * 1536 + h * 64;
    bf16x8 bq[2];
#pragma unroll
    for (int kh = 0; kh < 2; ++kh) {
        bf16x4 lo4 = *(const bf16x4*)(qptr + kh * 32 + l4 * 4);
        bf16x4 hi4 = *(const bf16x4*)(qptr + kh * 32 + 16 + l4 * 4);
        bq[kh] = __builtin_shufflevector(lo4, hi4, 0, 1, 2, 3, 4, 5, 6, 7);
    }

    const int band0 = max(0, qb - THRW);
    const int band1 = min(T_SEQ - 1, qb + 15 + THRW);
    const int i1s = band0, i1e = min(band1, lo - 1);
    const int i2s = max(band0, hi), i2e = band1;

    f32x4 O[4] = {{0.f,0.f,0.f,0.f},{0.f,0.f,0.f,0.f},{0.f,0.f,0.f,0.f},{0.f,0.f,0.f,0.f}};
    float m = -3.0e38f, lsum = 0.f;

#pragma unroll 1
    for (int seg = 0; seg < 2; ++seg) {
        const int s0 = seg ? i2s : i1s, s1 = seg ? i2e : i1e;
#pragma unroll 1
        for (int c0 = s0; c0 <= s1; c0 += 32) {
#pragma unroll
            for (int i = 0; i < 4; ++i) {
                const int idx = i * 64 + lane;
                const int row = idx >> 3, c = (idx & 7) * 8;
                const int kr = min(c0 + row, T_SEQ - 1);
                const uint4 kv = *(const uint4*)(qkv + rbase + (size_t)kr * 1536 + 512 + h * 64 + c);
                *(uint4*)&klds[row * KLD + c] = kv;
                const uint4 vv = *(const uint4*)(qkv + rbase + (size_t)kr * 1536 + 1024 + h * 64 + c);
                const ushort_t* vp = (const ushort_t*)&vv;
#pragma unroll
                for (int d = 0; d < 8; ++d) vlds[(c + d) * VLD + row] = vp[d];
            }
            f32x4 sacc[2];
#pragma unroll
            for (int ks = 0; ks < 2; ++ks) {
                f32x4 a = {0.f, 0.f, 0.f, 0.f};
#pragma unroll
                for (int kh = 0; kh < 2; ++kh) {
                    const ushort_t* kp = &klds[(16 * ks + l15) * KLD + kh * 32];
                    bf16x4 lo4 = *(const bf16x4*)(kp + l4 * 4);
                    bf16x4 hi4 = *(const bf16x4*)(kp + 16 + l4 * 4);
                    bf16x8 ak = __builtin_shufflevector(lo4, hi4, 0, 1, 2, 3, 4, 5, 6, 7);
                    a = __builtin_amdgcn_mfma_f32_16x16x32_bf16(ak, bq[kh], a, 0, 0, 0);
                }
                sacc[ks] = a;
            }
            float sv[8];
            bool vld[8];
            float cm = -3.0e38f;
#pragma unroll
            for (int ks = 0; ks < 2; ++ks)
#pragma unroll
                for (int r = 0; r < 4; ++r) {
                    const int key = c0 + 16 * ks + 4 * l4 + r;
                    const int dist = (q > key) ? (q - key) : (key - q);
                    const bool v = (dist <= THRW) && (key < lo || key >= hi) && (key < T_SEQ);
                    const int ii = ks * 4 + r;
                    sv[ii] = sacc[ks][r] * 0.125f - (float)(dist / PERIODN);
                    vld[ii] = v;
                    cm = fmaxf(cm, v ? sv[ii] : -3.0e38f);
                }
            cm = fmaxf(cm, __shfl_xor(cm, 16));
            cm = fmaxf(cm, __shfl_xor(cm, 32));
            const float mnew = fmaxf(m, cm);
            const float sc = __expf(m - mnew);
            m = mnew;
            float p[8], psum = 0.f;
#pragma unroll
            for (int ii = 0; ii < 8; ++ii) {
                p[ii] = vld[ii] ? __expf(sv[ii] - mnew) : 0.f;
                psum += p[ii];
            }
            psum += __shfl_xor(psum, 16);
            psum += __shfl_xor(psum, 32);
            lsum = lsum * sc + psum;
#pragma unroll
            for (int ds = 0; ds < 4; ++ds) O[ds] *= sc;
            bf16x8 pb;
#pragma unroll
            for (int ii = 0; ii < 8; ++ii) pb[ii] = (__bf16)p[ii];
#pragma unroll
            for (int ds = 0; ds < 4; ++ds) {
                const ushort_t* vp2 = &vlds[(16 * ds + l15) * VLD];
                bf16x4 lo4 = *(const bf16x4*)(vp2 + 4 * l4);
                bf16x4 hi4 = *(const bf16x4*)(vp2 + 16 + 4 * l4);
                bf16x8 av = __builtin_shufflevector(lo4, hi4, 0, 1, 2, 3, 4, 5, 6, 7);
                O[ds] = __builtin_amdgcn_mfma_f32_16x16x32_bf16(av, pb, O[ds], 0, 0, 0);
            }
        }
    }
    if (l15 <= nr) {
        const float inv = 1.0f / lsum;
        ushort_t* op = attout + (size_t)(b * T_SEQ + qb + l15) * DMODEL + h * 64;
#pragma unroll
        for (int ds = 0; ds < 4; ++ds)
#pragma unroll
            for (int r = 0; r < 4; ++r)
                op[16 * ds + 4 * l4 + r] = f2bf(O[ds][r] * inv);
    }
}

// ---------------------------------------------------------------------------
extern "C" void kernel_launch(void* const* d_in, const int* in_sizes, int n_in,
                              void* d_out, int out_size, void* d_ws, size_t ws_size,
                              hipStream_t stream) {
    const float* motion = (const float*)d_in[0];
    const float* traj   = (const float*)d_in[1];
    const float* me_w1  = (const float*)d_in[2];
    const float* me_b1  = (const float*)d_in[3];
    const float* me_w2  = (const float*)d_in[4];
    const float* me_b2  = (const float*)d_in[5];
    const float* wq = (const float*)d_in[6];
    const float* bq = (const float*)d_in[7];
    const float* wk = (const float*)d_in[8];
    const float* bk = (const float*)d_in[9];
    const float* wv = (const float*)d_in[10];
    const float* bv = (const float*)d_in[11];
    const float* wo = (const float*)d_in[12];
    const float* bo = (const float*)d_in[13];
    const float* ln1_g = (const float*)d_in[14];
    const float* ln1_b = (const float*)d_in[15];
    const float* ffn_w1 = (const float*)d_in[16];
    const float* ffn_b1 = (const float*)d_in[17];
    const float* ffn_w2 = (const float*)d_in[18];
    const float* ffn_b2 = (const float*)d_in[19];
    const float* ln2_g = (const float*)d_in[20];
    const float* ln2_b = (const float*)d_in[21];
    const float* fln_g = (const float*)d_in[22];
    const float* fln_b = (const float*)d_in[23];
    const float* dec_w1 = (const float*)d_in[24];
    const float* dec_b1 = (const float*)d_in[25];
    const float* dec_w2 = (const float*)d_in[26];
    const float* dec_b2 = (const float*)d_in[27];

    float* out = (float*)d_out;
    float* mask_out = out + (size_t)MROWS * DMOTION;

    char* base = (char*)d_ws;
    auto alloc = [&](size_t bytes) { char* p = base; base += (bytes + 255) & ~(size_t)255; return p; };

    ushort_t* qkvt  = (ushort_t*)alloc((size_t)NLAYERS * 1536 * 512 * 2);
    ushort_t* wot   = (ushort_t*)alloc((size_t)NLAYERS * 512 * 512 * 2);
    ushort_t* ffn1t = (ushort_t*)alloc((size_t)NLAYERS * 2048 * 512 * 2);
    ushort_t* ffn2t = (ushort_t*)alloc((size_t)NLAYERS * 512 * 2048 * 2);
    ushort_t* mew1t = (ushort_t*)alloc((size_t)512 * KIN * 2);
    ushort_t* mew2t = (ushort_t*)alloc((size_t)512 * 512 * 2);
    ushort_t* dec1t = (ushort_t*)alloc((size_t)512 * 512 * 2);
    ushort_t* dec2t = (ushort_t*)alloc((size_t)256 * 512 * 2);
    float*    bqkv  = (float*)alloc((size_t)NLAYERS * 1536 * 4);
    float*    pe15  = (float*)alloc((size_t)PERIODN * DMODEL * 4);
    float*    hp    = (float*)alloc((size_t)NB * 8 * 512 * 4);
    float*    vm    = (float*)alloc((size_t)NB * 512 * 4);
    float*    vmo   = (float*)alloc((size_t)NB * 512 * 4);
    ushort_t* hin   = (ushort_t*)alloc((size_t)MROWS * KIN * 2);
    float*    x     = (float*)alloc((size_t)MROWS * DMODEL * 4);
    ushort_t* h     = (ushort_t*)alloc((size_t)MROWS * DMODEL * 2);
    ushort_t* qkv   = (ushort_t*)alloc((size_t)MROWS * 1536 * 2);
    ushort_t* ff    = (ushort_t*)alloc((size_t)MROWS * DFF * 2);

    const dim3 blk(256);
    pe_k<<<(PERIODN * DMODEL + 255) / 256, blk, 0, stream>>>(pe15);
    build_k<<<(MROWS * KIN + 255) / 256, blk, 0, stream>>>(motion, traj, hin, mask_out);

    tconv_qkv_k<<<dim3(16, 16, 18), blk, 0, stream>>>(wq, wk, wv, qkvt);
    tconv_k<<<dim3(16, 16, 6), blk, 0, stream>>>(wo, 512 * 512, wot, 512 * 512, 512, 512, 512);
    tconv_k<<<dim3(64, 16, 6), blk, 0, stream>>>(ffn_w1, 512 * 2048, ffn1t, 2048 * 512, 512, 2048, 512);
    tconv_k<<<dim3(16, 64, 6), blk, 0, stream>>>(ffn_w2, 2048 * 512, ffn2t, 512 * 2048, 2048, 512, 2048);
    tconv_k<<<dim3(16, 12, 1), blk, 0, stream>>>(me_w1, 0, mew1t, 0, 262, 512, KIN);
    tconv_k<<<dim3(16, 16, 1), blk, 0, stream>>>(me_w2, 0, mew2t, 0, 512, 512, 512);
    tconv_k<<<dim3(16, 16, 1), blk, 0, stream>>>(dec_w1, 0, dec1t, 0, 512, 512, 512);
    tconv_k<<<dim3(8, 16, 1),  blk, 0, stream>>>(dec_w2, 0, dec2t, 0, 512, 256, 512);
    bcat_k<<<(NLAYERS * 1536 + 255) / 256, blk, 0, stream>>>(bq, bk, bv, bqkv);

    const dim3 gs512(8, 96), gsff(32, 96), gs256(4, 96);

    // motion encoder
    qgemm_k<1, false, false, true ><<<gs512, blk, 0, stream>>>(hin, KIN, mew1t, me_b1, nullptr, nullptr, h, 512);
    qgemm_k<1, false, true,  false><<<gs512, blk, 0, stream>>>(h, 512, mew2t, me_b2, nullptr, pe15, x, 512);

    for (int i = 0; i < NLAYERS; ++i) {
        const int lo = CTXF + THRW * i;
        const int hi = (T_SEQ - 1) - THRW * i;
        int qlow_end = lo + 127;
        int qhi0 = hi - 128;
        int nlow, ninact;
        if (qhi0 <= qlow_end + 1) {
            nlow = T_SEQ; qhi0 = T_SEQ; ninact = 0;
        } else {
            nlow = qlow_end + 1;
            ninact = qhi0 - nlow;
        }
        const int tl2 = (nlow + 15) / 16;
        const int th2 = (T_SEQ - qhi0 + 15) / 16;
        const int st  = tl2 + th2;
        // packed-row geometry: queries (active) and keys (allowed)
        const int nact_q = nlow + (T_SEQ - qhi0);
        const int tpb_q  = (nact_q + 31) / 32;
        const int nkeys  = lo + (T_SEQ - hi);
        const int tpb_kv = (nkeys + 31) / 32;

        const ushort_t* qw  = qkvt + (size_t)i * 1536 * 512;             // Q rows
        const ushort_t* kvw = qw + (size_t)512 * 512;                    // K,V rows
        const ushort_t* vw  = qw + (size_t)1024 * 512;                   // V rows
        const float* bq_i   = bqkv + i * 1536;

        ln_k<<<MROWS / 4, blk, 0, stream>>>(x, ln1_g + i * 512, ln1_b + i * 512, h);
        // Q for active query rows only
        pgemm_k<false, true><<<dim3(8, 2 * tpb_q), blk, 0, stream>>>(
            h, qw, bq_i, nullptr, qkv, 1536, tpb_q, nlow, qhi0, nact_q);
        // K,V for allowed key rows only (N = 1024 -> cols 512..1535)
        pgemm_k<false, true><<<dim3(16, 2 * tpb_kv), blk, 0, stream>>>(
            h, kvw, bq_i + 512, nullptr, qkv + 512, 1536, tpb_kv, lo, hi, nkeys);
        if (ninact > 0) {
            vsum_k<<<dim3(NB, 8), dim3(1024), 0, stream>>>(h, hp);
            vdot_k<<<dim3(NB, 4), blk, 0, stream>>>(hp, vw, bq_i + 1024, vm);
            gemv_k<<<dim3(NB, 4), blk, 0, stream>>>(vm, wot + (size_t)i * 512 * 512, bo + i * 512, vmo);
            xadd_k<<<dim3(ninact, NB), blk, 0, stream>>>(vmo, x, nlow);
        }
        attn3_k<<<dim3((st + 3) / 4, NHEADS, NB), blk, 0, stream>>>(qkv, h, lo, hi, nlow, qhi0, tl2, st);
        // out-proj over active rows only, residual into x
        pgemm_k<true, false><<<dim3(8, 2 * tpb_q), blk, 0, stream>>>(
            h, wot + (size_t)i * 512 * 512, bo + i * 512, x, x, 512, tpb_q, nlow, qhi0, nact_q);
        ln_k<<<MROWS / 4, blk, 0, stream>>>(x, ln2_g + i * 512, ln2_b + i * 512, h);
        qgemm_k<2, false, false, true><<<gsff, blk, 0, stream>>>(h, 512, ffn1t + (size_t)i * 2048 * 512, ffn_b1 + i * 2048, nullptr, nullptr, ff, 2048);
        qgemm_k<0, true, false, false><<<gs512, blk, 0, stream>>>(ff, 2048, ffn2t + (size_t)i * 512 * 2048, ffn_b2 + i * 512, x, nullptr, x, 512);
    }

    // decoder: dec1 (leaky) -> dec2 fused with final blend (ACT=3, res=motion)
    ln_k<<<MROWS / 4, blk, 0, stream>>>(x, fln_g, fln_b, h);
    qgemm_k<1, false, false, true ><<<gs512, blk, 0, stream>>>(h, 512, dec1t, dec_b1, nullptr, nullptr, ff, 512);
    qgemm_k<3, false, false, false><<<gs256, blk, 0, stream>>>(ff, 512, dec2t, dec_b2, motion, nullptr, out, 256);
}